// Round 1
// baseline (166.216 us; speedup 1.0000x reference)
//
#include <hip/hip_runtime.h>
#include <math.h>

#define DI   128
#define CIN  64
#define NOUT 256
#define HH   64
#define WW   64
#define LL   4096
#define KK   4
#define NST  16
#define RR   4
#define CDBL 36
#define NC   128   // number of chunks per sequence
#define SC   32    // chunk length = LL/NC

__device__ __forceinline__ float sigmoidf_(float x){ return 1.f/(1.f+__expf(-x)); }
__device__ __forceinline__ float softplusf_(float x){ return x>20.f ? x : __logf(1.f+__expf(x)); }
__device__ __forceinline__ void unpack4(float4 v, float* p){ p[0]=v.x; p[1]=v.y; p[2]=v.z; p[3]=v.w; }

// ---------------- K1: xz = x @ in_proj_w.T ; split into xin, z ----------------
// grid 256 blocks (16 l each) x 256 threads (thread = out channel)
__global__ __launch_bounds__(256) void k_inproj(const float* __restrict__ x,
        const float* __restrict__ wip, float* __restrict__ xin, float* __restrict__ z){
  int oc = threadIdx.x;
  int l0 = blockIdx.x * 16;
  float acc[16];
#pragma unroll
  for(int i=0;i<16;++i) acc[i]=0.f;
#pragma unroll 4
  for(int c4=0;c4<16;++c4){
    float4 w4 = *(const float4*)(wip + oc*CIN + c4*4);
#pragma unroll
    for(int li=0; li<16; ++li){
      float4 x4 = *(const float4*)(x + (l0+li)*CIN + c4*4);
      acc[li] += x4.x*w4.x + x4.y*w4.y + x4.z*w4.z + x4.w*w4.w;
    }
  }
#pragma unroll
  for(int li=0; li<16; ++li){
    float v = acc[li];
    if(oc < DI) xin[(l0+li)*DI + oc] = v;
    else        z[(l0+li)*DI + (oc-DI)] = v;
  }
}

// ---------------- K2: depthwise 3x3 conv (SAME) + bias + SiLU ----------------
// grid 2048 x 256 (2 pixels x 128 d per block)
__global__ __launch_bounds__(256) void k_conv(const float* __restrict__ xin,
        const float* __restrict__ cw, const float* __restrict__ cb, float* __restrict__ xf){
  int t = threadIdx.x;
  int d = t & (DI-1);
  int l = blockIdx.x*2 + (t>>7);
  int hh = l >> 6, ww = l & 63;
  float acc = cb[d];
#pragma unroll
  for(int dh=-1; dh<=1; ++dh){
    int h2 = hh+dh; if(h2<0||h2>=HH) continue;
#pragma unroll
    for(int dw=-1; dw<=1; ++dw){
      int w2 = ww+dw; if(w2<0||w2>=WW) continue;
      acc += xin[(h2*WW+w2)*DI + d] * cw[d*9 + (dh+1)*3 + (dw+1)];
    }
  }
  xf[l*DI+d] = acc * sigmoidf_(acc);
}

// ---------------- K3a: x_dbl[k][l][c] = sum_d xf[ids[k][l]][d] * xpw[k][c][d] ----------------
// thread = (k, l, cquad of 9 c's); grid 256 x 256
__global__ __launch_bounds__(256) void k_xdbl(const float* __restrict__ xf,
        const float* __restrict__ xpw, const int* __restrict__ ids, float* __restrict__ xdbl){
  int tg = blockIdx.x*256 + threadIdx.x;
  int cq = tg & 3;
  int l  = (tg>>2) & (LL-1);
  int k  = tg >> 14;
  int row = ids[k*LL + l];
  const float* xr = xf + row*DI;
  const float* wr = xpw + (k*CDBL + cq*9)*DI;
  float acc[9];
#pragma unroll
  for(int j=0;j<9;++j) acc[j]=0.f;
  for(int d4=0; d4<32; ++d4){
    float4 x4 = *(const float4*)(xr + d4*4);
#pragma unroll
    for(int j=0;j<9;++j){
      float4 w4 = *(const float4*)(wr + j*DI + d4*4);
      acc[j] += x4.x*w4.x + x4.y*w4.y + x4.z*w4.z + x4.w*w4.w;
    }
  }
  float* o = xdbl + (k*LL+l)*CDBL + cq*9;
#pragma unroll
  for(int j=0;j<9;++j) o[j] = acc[j];
}

// ---------------- K3b: delta = softplus(dt_projs_weight @ dts + bias) ----------------
// thread = (k, l, dquad); grid 2048 x 256
__global__ __launch_bounds__(256) void k_delta(const float* __restrict__ xdbl,
        const float* __restrict__ dtw, const float* __restrict__ dtb, float* __restrict__ delta){
  int tg = blockIdx.x*256 + threadIdx.x;
  int dq = tg & 31;
  int l  = (tg>>5) & (LL-1);
  int k  = tg >> 17;
  float4 dts = *(const float4*)(xdbl + (k*LL+l)*CDBL);
  float outv[4];
#pragma unroll
  for(int j=0;j<4;++j){
    int d = dq*4+j;
    float4 w4 = *(const float4*)(dtw + (k*DI+d)*RR);
    float v = dts.x*w4.x + dts.y*w4.y + dts.z*w4.z + dts.w*w4.w + dtb[k*DI+d];
    outv[j] = softplusf_(v);
  }
  *(float4*)(delta + (k*LL+l)*DI + dq*4) = make_float4(outv[0],outv[1],outv[2],outv[3]);
}

// ---------------- K4a: per-chunk scan pass 1 -> (sum_delta, h_chunk) ----------------
// grid (NC, K) x 128 threads (thread = d), 16 states per thread
__global__ __launch_bounds__(128) void k_scan1(const float* __restrict__ delta,
        const float* __restrict__ xf, const float* __restrict__ xdbl,
        const int* __restrict__ ids, const float* __restrict__ alog,
        float* __restrict__ Hc, float* __restrict__ SD){
  int d = threadIdx.x;
  int c = blockIdx.x, k = blockIdx.y;
  float An[NST];
#pragma unroll
  for(int n4=0;n4<4;++n4){
    float4 a4 = *(const float4*)(alog + (k*DI+d)*NST + n4*4);
    An[n4*4+0] = -__expf(a4.x); An[n4*4+1] = -__expf(a4.y);
    An[n4*4+2] = -__expf(a4.z); An[n4*4+3] = -__expf(a4.w);
  }
  float h[NST];
#pragma unroll
  for(int n=0;n<NST;++n) h[n]=0.f;
  float sd = 0.f;
  for(int i=0;i<SC;++i){
    int l = c*SC + i;
    float dl = delta[(k*LL+l)*DI + d];
    int row = ids[k*LL+l];
    float u = xf[row*DI + d];
    const float4* xr = (const float4*)(xdbl + (k*LL+l)*CDBL);
    float B[NST];
    unpack4(xr[1], B+0); unpack4(xr[2], B+4); unpack4(xr[3], B+8); unpack4(xr[4], B+12);
    float du = dl*u;
    sd += dl;
#pragma unroll
    for(int n=0;n<NST;++n) h[n] = __expf(dl*An[n])*h[n] + du*B[n];
  }
  float* hp = Hc + ((k*NC+c)*DI + d)*NST;
#pragma unroll
  for(int n4=0;n4<4;++n4)
    *(float4*)(hp+n4*4) = make_float4(h[n4*4],h[n4*4+1],h[n4*4+2],h[n4*4+3]);
  SD[(k*NC+c)*DI + d] = sd;
}

// ---------------- K4b: inter-chunk propagation (exclusive) ----------------
// thread = (k,d,n); grid 32 x 256
__global__ __launch_bounds__(256) void k_scanmid(const float* __restrict__ SD,
        const float* __restrict__ Hc, const float* __restrict__ alog, float* __restrict__ hin){
  int tg = blockIdx.x*256 + threadIdx.x;
  int n = tg & (NST-1);
  int d = (tg>>4) & (DI-1);
  int k = tg >> 11;
  float An = -__expf(alog[(k*DI+d)*NST + n]);
  float h = 0.f;
  for(int c=0;c<NC;++c){
    int base = (k*NC+c)*DI + d;
    hin[base*NST + n] = h;
    h = __expf(An*SD[base])*h + Hc[base*NST+n];
  }
}

// ---------------- K4c: per-chunk scan pass 2 -> y + pool partials ----------------
__global__ __launch_bounds__(128) void k_scan2(const float* __restrict__ delta,
        const float* __restrict__ xf, const float* __restrict__ xdbl,
        const int* __restrict__ ids, const float* __restrict__ alog,
        const float* __restrict__ hin, const float* __restrict__ Dsp,
        float* __restrict__ ysc, float* __restrict__ ppart){
  int d = threadIdx.x;
  int c = blockIdx.x, k = blockIdx.y;
  float An[NST];
#pragma unroll
  for(int n4=0;n4<4;++n4){
    float4 a4 = *(const float4*)(alog + (k*DI+d)*NST + n4*4);
    An[n4*4+0] = -__expf(a4.x); An[n4*4+1] = -__expf(a4.y);
    An[n4*4+2] = -__expf(a4.z); An[n4*4+3] = -__expf(a4.w);
  }
  float h[NST];
  const float* hp = hin + ((k*NC+c)*DI + d)*NST;
#pragma unroll
  for(int n4=0;n4<4;++n4){
    float4 h4 = *(const float4*)(hp + n4*4);
    h[n4*4+0]=h4.x; h[n4*4+1]=h4.y; h[n4*4+2]=h4.z; h[n4*4+3]=h4.w;
  }
  float Dv = Dsp[k*DI+d];
  float pacc = 0.f;
  for(int i=0;i<SC;++i){
    int l = c*SC + i;
    float dl = delta[(k*LL+l)*DI + d];
    int row = ids[k*LL+l];
    float u = xf[row*DI + d];
    const float4* xr = (const float4*)(xdbl + (k*LL+l)*CDBL);
    float B[NST], Cc[NST];
    unpack4(xr[1], B+0); unpack4(xr[2], B+4); unpack4(xr[3], B+8); unpack4(xr[4], B+12);
    unpack4(xr[5], Cc+0); unpack4(xr[6], Cc+4); unpack4(xr[7], Cc+8); unpack4(xr[8], Cc+12);
    float du = dl*u;
    float y = 0.f;
#pragma unroll
    for(int n=0;n<NST;++n) h[n] = __expf(dl*An[n])*h[n] + du*B[n];
#pragma unroll
    for(int n=0;n<NST;++n) y += h[n]*Cc[n];
    float yl = y + Dv*u;
    ysc[(k*LL+l)*DI + d] = yl;
    pacc += yl;
  }
  ppart[(k*NC+c)*DI + d] = pacc;
}

// ---------------- K5b: pooled[k][d] = mean over l ----------------
__global__ __launch_bounds__(256) void k_pool(const float* __restrict__ ppart, float* __restrict__ pooled){
  int k = blockIdx.x;
  int t = threadIdx.x;
  int d = t & 127, cs = t >> 7;
  float a = 0.f;
  for(int c=cs; c<NC; c+=2) a += ppart[(k*NC+c)*DI + d];
  __shared__ float red[256];
  red[t] = a;
  __syncthreads();
  if(t < 128) pooled[k*DI + t] = (red[t] + red[t+128]) * (1.f/(float)LL);
}

// ---------------- K5c: gate + inverse-gather + K-sum + LN + silu(z) mul + out_proj ----------------
// grid 256 blocks (16 pixels each) x 256 threads (2 pixel-slots x 128 d)
__global__ __launch_bounds__(256) void k_final(const float* __restrict__ ysc,
        const float* __restrict__ z, const int* __restrict__ inv,
        const float* __restrict__ pooled, const float* __restrict__ gw, const float* __restrict__ gb,
        const float* __restrict__ nw, const float* __restrict__ nb,
        const float* __restrict__ wout, float* __restrict__ out){
  __shared__ float lw[DI*68];    // out_proj_w transposed: [d][c], pad 68
  __shared__ float ls[16*132];   // yn*silu(z): [pixel][d], pad 132
  __shared__ float red2[8];
  int t = threadIdx.x;
#pragma unroll
  for(int j=0;j<32;++j){ int e = j*256+t; lw[(e&127)*68 + (e>>7)] = wout[e]; }
  int d  = t & 127;
  int hf = t >> 7;
  float gate[4];
#pragma unroll
  for(int kk=0;kk<4;++kk){
    const float* gr = gw + (d*4+kk)*4;
    float s = gr[0]*pooled[0*DI+d] + gr[1]*pooled[1*DI+d]
            + gr[2]*pooled[2*DI+d] + gr[3]*pooled[3*DI+d] + gb[d*4+kk];
    gate[kk] = sigmoidf_(s);
  }
  float nwv = nw[d], nbv = nb[d];
  int l0 = blockIdx.x*16;
  int wid = t >> 6;
  __syncthreads();
  for(int it=0; it<8; ++it){
    int ll = it*2 + hf;
    int l  = l0 + ll;
    float v = 0.f;
#pragma unroll
    for(int kk=0;kk<4;++kk){
      int p = inv[kk*LL + l];
      v += gate[kk] * ysc[(kk*LL+p)*DI + d];
    }
    float s1 = v, s2 = v*v;
#pragma unroll
    for(int off=1; off<64; off<<=1){ s1 += __shfl_xor(s1, off); s2 += __shfl_xor(s2, off); }
    if((t&63)==0){ red2[wid*2] = s1; red2[wid*2+1] = s2; }
    __syncthreads();
    int pw = wid^1;
    float tot1 = s1 + red2[pw*2], tot2 = s2 + red2[pw*2+1];
    float mu   = tot1*(1.f/128.f);
    float var  = tot2*(1.f/128.f) - mu*mu;
    float rstd = rsqrtf(var + 1e-5f);
    float zz   = z[l*DI + d];
    float val  = ((v-mu)*rstd*nwv + nbv) * (zz * sigmoidf_(zz));
    ls[ll*132 + d] = val;
    __syncthreads();
  }
  // out_proj: 16 pixels x 64 c; thread = (pixel, c-quad)
  int ll = t >> 4, cq = t & 15;
  float a0=0.f, a1=0.f, a2=0.f, a3=0.f;
  for(int d4=0; d4<32; ++d4){
    float4 s4 = *(const float4*)&ls[ll*132 + d4*4];
    float4 w0 = *(const float4*)&lw[(d4*4+0)*68 + cq*4];
    float4 w1 = *(const float4*)&lw[(d4*4+1)*68 + cq*4];
    float4 w2 = *(const float4*)&lw[(d4*4+2)*68 + cq*4];
    float4 w3 = *(const float4*)&lw[(d4*4+3)*68 + cq*4];
    a0 += s4.x*w0.x + s4.y*w1.x + s4.z*w2.x + s4.w*w3.x;
    a1 += s4.x*w0.y + s4.y*w1.y + s4.z*w2.y + s4.w*w3.y;
    a2 += s4.x*w0.z + s4.y*w1.z + s4.z*w2.z + s4.w*w3.z;
    a3 += s4.x*w0.w + s4.y*w1.w + s4.z*w2.w + s4.w*w3.w;
  }
  *(float4*)(out + (l0+ll)*CIN + cq*4) = make_float4(a0,a1,a2,a3);
}

extern "C" void kernel_launch(void* const* d_in, const int* in_sizes, int n_in,
                              void* d_out, int out_size, void* d_ws, size_t ws_size,
                              hipStream_t stream){
  const float* x    = (const float*)d_in[0];
  const float* ipw  = (const float*)d_in[1];
  const float* cw   = (const float*)d_in[2];
  const float* cb   = (const float*)d_in[3];
  const float* xpw  = (const float*)d_in[4];
  const float* dtw  = (const float*)d_in[5];
  const float* dtb  = (const float*)d_in[6];
  const float* alog = (const float*)d_in[7];
  const float* Dsp  = (const float*)d_in[8];
  const float* gw   = (const float*)d_in[9];
  const float* gb   = (const float*)d_in[10];
  const float* nw   = (const float*)d_in[11];
  const float* nb   = (const float*)d_in[12];
  const float* wout = (const float*)d_in[13];
  const int*   ids  = (const int*)d_in[14];
  const int*   inv  = (const int*)d_in[15];
  float* out = (float*)d_out;

  float* w     = (float*)d_ws;
  float* z     = w;                 // L*DI           = 524288
  float* xin   = z     + 524288;    // L*DI           = 524288
  float* xf    = xin   + 524288;    // L*DI           = 524288
  float* xdbl  = xf    + 524288;    // K*L*36         = 589824
  float* delta = xdbl  + 589824;    // K*L*DI         = 2097152
  float* ysc   = delta + 2097152;   // K*L*DI         = 2097152
  float* SDb   = ysc   + 2097152;   // K*NC*DI        = 65536
  float* Hcb   = SDb   + 65536;     // K*NC*DI*NST    = 1048576
  float* hinb  = Hcb   + 1048576;   // K*NC*DI*NST    = 1048576
  float* ppart = hinb  + 1048576;   // K*NC*DI        = 65536
  float* pooled= ppart + 65536;     // K*DI           = 512
  // total ~8.59M floats = ~34.4 MB of d_ws

  hipLaunchKernelGGL(k_inproj,  dim3(256),     dim3(256), 0, stream, x, ipw, xin, z);
  hipLaunchKernelGGL(k_conv,    dim3(2048),    dim3(256), 0, stream, xin, cw, cb, xf);
  hipLaunchKernelGGL(k_xdbl,    dim3(256),     dim3(256), 0, stream, xf, xpw, ids, xdbl);
  hipLaunchKernelGGL(k_delta,   dim3(2048),    dim3(256), 0, stream, xdbl, dtw, dtb, delta);
  hipLaunchKernelGGL(k_scan1,   dim3(NC,KK),   dim3(128), 0, stream, delta, xf, xdbl, ids, alog, Hcb, SDb);
  hipLaunchKernelGGL(k_scanmid, dim3(32),      dim3(256), 0, stream, SDb, Hcb, alog, hinb);
  hipLaunchKernelGGL(k_scan2,   dim3(NC,KK),   dim3(128), 0, stream, delta, xf, xdbl, ids, alog, hinb, Dsp, ysc, ppart);
  hipLaunchKernelGGL(k_pool,    dim3(KK),      dim3(256), 0, stream, ppart, pooled);
  hipLaunchKernelGGL(k_final,   dim3(256),     dim3(256), 0, stream, ysc, z, inv, pooled, gw, gb, nw, nb, wout, out);
}